// Round 5
// baseline (283.577 us; speedup 1.0000x reference)
//
#include <hip/hip_runtime.h>
#include <stdint.h>

#define AQ_MAX 15.0f
#define BN_EPS 1e-5f

// ---------------------------------------------------------------------------
// Merged prep: per-output-channel int4 symmetric weight fake-quant + BN fold.
// P layout (floats): wq1[32*28]@0 wq2[288]@896 wq3[1536]@1184 wq4[432]@2720
//   wq5[3072]@3152 | inv1@6224 beta1@6256 inv2@6288 beta2@6320 inv3@6352
//   beta3@6400 inv4@6448 beta4@6496 inv5@6544 beta5@6608 (end 6672)
// ---------------------------------------------------------------------------
__global__ __launch_bounds__(64) void prep_all(
    const float* __restrict__ wA, const float* __restrict__ gA,
    const float* __restrict__ bA, const float* __restrict__ mA,
    const float* __restrict__ vA,
    const float* __restrict__ wB, const float* __restrict__ gB,
    const float* __restrict__ bB, const float* __restrict__ mB,
    const float* __restrict__ vB,
    const float* __restrict__ wC, const float* __restrict__ gC,
    const float* __restrict__ bC, const float* __restrict__ mC,
    const float* __restrict__ vC,
    const float* __restrict__ wD, const float* __restrict__ gD,
    const float* __restrict__ bD, const float* __restrict__ mD,
    const float* __restrict__ vD,
    const float* __restrict__ wE, const float* __restrict__ gE,
    const float* __restrict__ bE, const float* __restrict__ mE,
    const float* __restrict__ vE,
    float* __restrict__ P) {
  int blk = blockIdx.x, t = threadIdx.x;
  const float *w, *g, *b, *m, *v;
  float *wq, *inv, *beta;
  int K, KP, c;
  if (blk < 32) {
    c = blk; w = wA; g = gA; b = bA; m = mA; v = vA; K = 27; KP = 28;
    wq = P + 0; inv = P + 6224; beta = P + 6256;
  } else if (blk < 64) {
    c = blk - 32; w = wB; g = gB; b = bB; m = mB; v = vB; K = 9; KP = 9;
    wq = P + 896; inv = P + 6288; beta = P + 6320;
  } else if (blk < 112) {
    c = blk - 64; w = wC; g = gC; b = bC; m = mC; v = vC; K = 32; KP = 32;
    wq = P + 1184; inv = P + 6352; beta = P + 6400;
  } else if (blk < 160) {
    c = blk - 112; w = wD; g = gD; b = bD; m = mD; v = vD; K = 9; KP = 9;
    wq = P + 2720; inv = P + 6448; beta = P + 6496;
  } else {
    c = blk - 160; w = wE; g = gE; b = bE; m = mE; v = vE; K = 48; KP = 48;
    wq = P + 3152; inv = P + 6544; beta = P + 6608;
  }
  const float* wc = w + (size_t)c * K;
  float a = (t < K) ? fabsf(wc[t]) : 0.0f;
#pragma unroll
  for (int off = 32; off >= 1; off >>= 1) a = fmaxf(a, __shfl_xor(a, off));
  float s = fmaxf(a / 7.0f, 1e-8f);
  if (t < K) {
    float q = rintf(wc[t] / s);  // round half-to-even, same as jnp.round
    q = fminf(7.0f, fmaxf(-7.0f, q));
    wq[(size_t)c * KP + t] = q * s;
  } else if (t < KP) {
    wq[(size_t)c * KP + t] = 0.0f;
  }
  if (t == 0) {
    float iv = g[c] / sqrtf(v[c] + BN_EPS);
    inv[c] = iv;
    beta[c] = b[c] - m[c] * iv;
  }
}

// ---------------------------------------------------------------------------
// Stage 1: conv 3x3 s2 p0, 3->32, fp32 [8,3,512,1024] -> uint4 codes
// [8,32,255,512(pad)]. Lane = oc; weights persistent in VGPRs.
// __launch_bounds__(256, 4): VGPR cap 128 — the design needs ~90 live regs
// (w[27]+rr[17]+acc[8]+addr); default heuristic chose 36 VGPR and spilled
// (round-4 counter evidence), bloating VALU ~2.2x.
// ---------------------------------------------------------------------------
__global__ __launch_bounds__(256, 4) void stage1_kernel(
    const float* __restrict__ x, const float* __restrict__ P,
    const float* __restrict__ s1p, uint8_t* __restrict__ out) {
  __shared__ float tin[9 * 132];     // (ic*3+kh) x 132 cols
  __shared__ uint8_t tout[32 * 68];  // oc x 64 codes (+4 pad)
  int bid = blockIdx.x;              // n*255*8 + oy*8 + oxg
  int oxg = bid & 7;
  int t2 = bid >> 3;
  int oy = t2 % 255;
  int n = t2 / 255;
  int iy = 2 * oy;
  int ix0 = oxg * 128;
  // stage input tile: 9 rows x 33 float4
  {
    const float* xb = x + ((size_t)n * 3) * 512 * 1024;
    int idx = threadIdx.x;
#pragma unroll
    for (int rep = 0; rep < 2; rep++, idx += 256) {
      if (idx < 297) {
        int r = idx / 33, c4 = idx % 33;  // r = ic*3+kh
        int ic = r / 3, kh = r % 3;
        int col = ix0 + c4 * 4;
        float4 f = make_float4(0.f, 0.f, 0.f, 0.f);
        if (col <= 1020)
          f = *(const float4*)(xb + ((size_t)ic * 512 + iy + kh) * 1024 + col);
        *(float4*)&tin[r * 132 + c4 * 4] = f;
      }
    }
  }
  int oc = threadIdx.x & 31;
  int pg = threadIdx.x >> 5;  // 0..7 -> px = pg*8 .. pg*8+7
  float w[28];
#pragma unroll
  for (int tI = 0; tI < 7; tI++) {
    float4 f = *(const float4*)(P + oc * 28 + 4 * tI);
    w[4 * tI] = f.x; w[4 * tI + 1] = f.y;
    w[4 * tI + 2] = f.z; w[4 * tI + 3] = f.w;
  }
  float iv = P[6224 + oc], bt = P[6256 + oc];
  float s1 = *s1p;
  __syncthreads();
  float acc[8] = {0, 0, 0, 0, 0, 0, 0, 0};
#pragma unroll
  for (int s = 0; s < 9; s++) {
    float rr[17];
    const float* rp = &tin[s * 132 + pg * 16];
#pragma unroll
    for (int tI = 0; tI < 4; tI++) {
      float4 f = *(const float4*)(rp + 4 * tI);
      rr[4 * tI] = f.x; rr[4 * tI + 1] = f.y;
      rr[4 * tI + 2] = f.z; rr[4 * tI + 3] = f.w;
    }
    rr[16] = rp[16];
#pragma unroll
    for (int kw = 0; kw < 3; kw++) {
      float wv = w[s * 3 + kw];
#pragma unroll
      for (int k = 0; k < 8; k++)
        acc[k] = fmaf(rr[2 * k + kw], wv, acc[k]);
    }
  }
  uint32_t pk0 = 0, pk1 = 0;
#pragma unroll
  for (int k = 0; k < 8; k++) {
    float y = fmaf(acc[k], iv, bt);
    uint32_t q = (uint32_t)fminf(AQ_MAX, fmaxf(0.0f, rintf(y / s1)));
    if (k < 4) pk0 |= q << (8 * k); else pk1 |= q << (8 * (k - 4));
  }
  *(uint32_t*)&tout[oc * 68 + pg * 8] = pk0;
  *(uint32_t*)&tout[oc * 68 + pg * 8 + 4] = pk1;
  __syncthreads();
  size_t obase = (((size_t)n * 32) * 255 + oy) * 512 + oxg * 64;
  int c4 = (threadIdx.x & 15) * 4;
  int ocs = threadIdx.x >> 4;  // 0..15
#pragma unroll
  for (int p = 0; p < 2; p++) {
    int o = p * 16 + ocs;
    uint32_t val = *(const uint32_t*)&tout[o * 68 + c4];
    *(uint32_t*)(out + obase + (size_t)o * (255 * 512) + c4) = val;
  }
}

// ---------------------------------------------------------------------------
// Depthwise 3x3 s2 p1, codes in -> codes out. 4 output px/thread.
// ---------------------------------------------------------------------------
template <int C, int IH, int IWL, int IWP, int OH, int OW>
__global__ __launch_bounds__(256) void dw_kernel(
    const uint8_t* __restrict__ in, const float* __restrict__ wq,
    const float* __restrict__ inv, const float* __restrict__ beta,
    const float* __restrict__ sin_p, const float* __restrict__ sout_p,
    uint8_t* __restrict__ out) {
  constexpr int GX = OW / 4;
  int tid = blockIdx.x * 256 + threadIdx.x;
  int oxg = tid % GX;
  int t2 = tid / GX;
  int oy = t2 % OH;
  int t3 = t2 / OH;
  int c = __builtin_amdgcn_readfirstlane(t3 % C);
  int n = __builtin_amdgcn_readfirstlane(t3 / C);
  float s_in = *sin_p, s_out = *sout_p;
  const float* wc = wq + c * 9;  // uniform -> s_load
  float w[9];
#pragma unroll
  for (int j = 0; j < 9; j++) w[j] = wc[j];
  float iv = inv[c], bt = beta[c];
  int c0 = oxg * 8;
  const uint8_t* chan = in + ((size_t)(n * C + c)) * IH * IWP;
  float xr[3][9];
#pragma unroll
  for (int kh = 0; kh < 3; kh++) {
    int iy = 2 * oy + kh - 1;
    if (iy >= 0 && iy < IH) {
      const uint8_t* rp = chan + (size_t)iy * IWP;
      uint2 u = *(const uint2*)(rp + c0);
      xr[kh][0] = (oxg > 0) ? (float)rp[c0 - 1] : 0.0f;
#pragma unroll
      for (int j = 0; j < 4; j++) xr[kh][1 + j] = (float)((u.x >> (8 * j)) & 255u);
#pragma unroll
      for (int j = 0; j < 4; j++) xr[kh][5 + j] = (float)((u.y >> (8 * j)) & 255u);
      if (IWL < IWP && oxg == GX - 1) xr[kh][8] = 0.0f;
    } else {
#pragma unroll
      for (int j = 0; j < 9; j++) xr[kh][j] = 0.0f;
    }
  }
#pragma unroll
  for (int kh = 0; kh < 3; kh++)
#pragma unroll
    for (int j = 0; j < 9; j++) xr[kh][j] *= s_in;
  float acc[4] = {0, 0, 0, 0};
#pragma unroll
  for (int kh = 0; kh < 3; kh++)
#pragma unroll
    for (int kw = 0; kw < 3; kw++) {
      float wv = w[kh * 3 + kw];
#pragma unroll
      for (int p = 0; p < 4; p++) acc[p] = fmaf(xr[kh][2 * p + kw], wv, acc[p]);
    }
  uint32_t pack = 0;
#pragma unroll
  for (int p = 0; p < 4; p++) {
    float y = fmaf(acc[p], iv, bt);
    float q = fminf(AQ_MAX, fmaxf(0.0f, rintf(y / s_out)));
    pack |= ((uint32_t)q) << (8 * p);
  }
  *(uint32_t*)(out + ((size_t)(n * C + c) * OH + oy) * OW + c0 / 2) = pack;
}

// ---------------------------------------------------------------------------
// Pointwise 1x1, oc-chunked across blocks (chunk wave-uniform -> s_load
// weights). 2 px/thread. FINAL=true writes dequantized fp32.
// ---------------------------------------------------------------------------
template <int IC, int OC, int CHUNK, int HW, bool FINAL>
__global__ __launch_bounds__(256, 4) void pw_kernel(
    const uint8_t* __restrict__ in, const float* __restrict__ Pw,
    const float* __restrict__ Pinv, const float* __restrict__ Pbeta,
    const float* __restrict__ sin_p, const float* __restrict__ sout_p,
    void* __restrict__ outv) {
  constexpr int NCH = OC / CHUNK;
  constexpr int PG = HW / 2;
  int bid = blockIdx.x;
  int chunk = bid % NCH;
  int pb = bid / NCH;
  int tpx = pb * 256 + threadIdx.x;
  int px0 = (tpx % PG) * 2;
  int n = __builtin_amdgcn_readfirstlane(tpx / PG);
  float s_in = *sin_p, s_out = *sout_p;
  const uint8_t* ib = in + (size_t)n * IC * HW + px0;
  float xa[IC], xb[IC];
#pragma unroll
  for (int ic = 0; ic < IC; ic++) {
    uint16_t u = *(const uint16_t*)(ib + (size_t)ic * HW);
    xa[ic] = (float)(u & 255u) * s_in;
    xb[ic] = (float)(u >> 8) * s_in;
  }
  int oc0 = chunk * CHUNK;
#pragma unroll 2
  for (int oc = oc0; oc < oc0 + CHUNK; oc++) {
    const float* wp = Pw + oc * IC;  // uniform -> s_load
    float w[IC];
#pragma unroll
    for (int ic = 0; ic < IC; ic++) w[ic] = wp[ic];
    float a0 = 0, a1 = 0;
#pragma unroll
    for (int ic = 0; ic < IC; ic++) {
      a0 = fmaf(xa[ic], w[ic], a0);
      a1 = fmaf(xb[ic], w[ic], a1);
    }
    float iv = Pinv[oc], bt = Pbeta[oc];
    float y0 = fmaf(a0, iv, bt), y1 = fmaf(a1, iv, bt);
    float q0 = fminf(AQ_MAX, fmaxf(0.0f, rintf(y0 / s_out)));
    float q1 = fminf(AQ_MAX, fmaxf(0.0f, rintf(y1 / s_out)));
    if (FINAL) {
      float2 o;
      o.x = q0 * s_out; o.y = q1 * s_out;
      *(float2*)((float*)outv + (size_t)(n * OC + oc) * HW + px0) = o;
    } else {
      uint16_t pk = (uint16_t)((uint32_t)q0 | ((uint32_t)q1 << 8));
      *(uint16_t*)((uint8_t*)outv + (size_t)(n * OC + oc) * HW + px0) = pk;
    }
  }
}

extern "C" void kernel_launch(void* const* d_in, const int* in_sizes, int n_in,
                              void* d_out, int out_size, void* d_ws, size_t ws_size,
                              hipStream_t stream) {
  const float* x    = (const float*)d_in[0];
  const float* w1   = (const float*)d_in[1];
  const float* g1   = (const float*)d_in[2];
  const float* b1   = (const float*)d_in[3];
  const float* m1   = (const float*)d_in[4];
  const float* v1   = (const float*)d_in[5];
  const float* s1   = (const float*)d_in[6];
  const float* wdw1 = (const float*)d_in[7];
  const float* g2   = (const float*)d_in[8];
  const float* b2   = (const float*)d_in[9];
  const float* m2   = (const float*)d_in[10];
  const float* v2   = (const float*)d_in[11];
  const float* s2   = (const float*)d_in[12];
  const float* wpw1 = (const float*)d_in[13];
  const float* g3   = (const float*)d_in[14];
  const float* b3   = (const float*)d_in[15];
  const float* m3   = (const float*)d_in[16];
  const float* v3   = (const float*)d_in[17];
  const float* s3   = (const float*)d_in[18];
  const float* wdw2 = (const float*)d_in[19];
  const float* g4   = (const float*)d_in[20];
  const float* b4   = (const float*)d_in[21];
  const float* m4   = (const float*)d_in[22];
  const float* v4   = (const float*)d_in[23];
  const float* s4   = (const float*)d_in[24];
  const float* wpw2 = (const float*)d_in[25];
  const float* g5   = (const float*)d_in[26];
  const float* b5   = (const float*)d_in[27];
  const float* m5   = (const float*)d_in[28];
  const float* v5   = (const float*)d_in[29];
  const float* s5   = (const float*)d_in[30];

  float* P = (float*)d_ws;
  float* wq2  = P + 896;
  float* wq3  = P + 1184;
  float* wq4  = P + 2720;
  float* wq5  = P + 3152;
  float* inv2 = P + 6288, *beta2 = P + 6320;
  float* inv3 = P + 6352, *beta3 = P + 6400;
  float* inv4 = P + 6448, *beta4 = P + 6496;
  float* inv5 = P + 6544, *beta5 = P + 6608;

  uint8_t* ws8 = (uint8_t*)d_ws;
  uint8_t* x1 = ws8 + 32768;            // [8,32,255,512] codes: 33,423,360 B
  uint8_t* x2 = x1 + 33423360;          // [8,32,128,256]:  8,388,608 B
  uint8_t* x3 = x2 + 8388608;           // [8,48,128,256]: 12,582,912 B
  uint8_t* x4 = ws8 + 32768;            // [8,48,64,128]: aliases x1 (dead)

  prep_all<<<224, 64, 0, stream>>>(w1, g1, b1, m1, v1,
                                   wdw1, g2, b2, m2, v2,
                                   wpw1, g3, b3, m3, v3,
                                   wdw2, g4, b4, m4, v4,
                                   wpw2, g5, b5, m5, v5, P);

  // Stage 1: blocks = 8n * 255oy * 8oxg
  stage1_kernel<<<16320, 256, 0, stream>>>(x, P, s1, x1);
  // dw1: 32ch, 255x511(512) -> 128x256
  dw_kernel<32, 255, 511, 512, 128, 256>
      <<<8192, 256, 0, stream>>>(x1, wq2, inv2, beta2, s1, s2, x2);
  // pw1: 32->48 @128x256, chunk 24 (2 chunks): 512 px-blocks * 2
  pw_kernel<32, 48, 24, 32768, false>
      <<<1024, 256, 0, stream>>>(x2, wq3, inv3, beta3, s2, s3, x3);
  // dw2: 48ch, 128x256 -> 64x128
  dw_kernel<48, 128, 256, 256, 64, 128>
      <<<3072, 256, 0, stream>>>(x3, wq4, inv4, beta4, s3, s4, x4);
  // pw2: 48->64 @64x128 -> fp32, chunk 8 (8 chunks): 128 px-blocks * 8
  pw_kernel<48, 64, 8, 8192, true>
      <<<1024, 256, 0, stream>>>(x4, wq5, inv5, beta5, s4, s5, (float*)d_out);
}

// Round 6
// 120.126 us; speedup vs baseline: 2.3607x; 2.3607x over previous
//
#include <hip/hip_runtime.h>
#include <stdint.h>

#define AQ_MAX 15.0f
#define BN_EPS 1e-5f

// ---------------------------------------------------------------------------
// Merged prep: per-output-channel int4 symmetric weight fake-quant + BN fold.
// P layout (floats): wq1[32*28]@0 wq2[288]@896 wq3[1536]@1184 wq4[432]@2720
//   wq5[3072]@3152 | inv1@6224 beta1@6256 inv2@6288 beta2@6320 inv3@6352
//   beta3@6400 inv4@6448 beta4@6496 inv5@6544 beta5@6608 (end 6672)
// ---------------------------------------------------------------------------
__global__ __launch_bounds__(64) void prep_all(
    const float* __restrict__ wA, const float* __restrict__ gA,
    const float* __restrict__ bA, const float* __restrict__ mA,
    const float* __restrict__ vA,
    const float* __restrict__ wB, const float* __restrict__ gB,
    const float* __restrict__ bB, const float* __restrict__ mB,
    const float* __restrict__ vB,
    const float* __restrict__ wC, const float* __restrict__ gC,
    const float* __restrict__ bC, const float* __restrict__ mC,
    const float* __restrict__ vC,
    const float* __restrict__ wD, const float* __restrict__ gD,
    const float* __restrict__ bD, const float* __restrict__ mD,
    const float* __restrict__ vD,
    const float* __restrict__ wE, const float* __restrict__ gE,
    const float* __restrict__ bE, const float* __restrict__ mE,
    const float* __restrict__ vE,
    float* __restrict__ P) {
  int blk = blockIdx.x, t = threadIdx.x;
  const float *w, *g, *b, *m, *v;
  float *wq, *inv, *beta;
  int K, KP, c;
  if (blk < 32) {
    c = blk; w = wA; g = gA; b = bA; m = mA; v = vA; K = 27; KP = 28;
    wq = P + 0; inv = P + 6224; beta = P + 6256;
  } else if (blk < 64) {
    c = blk - 32; w = wB; g = gB; b = bB; m = mB; v = vB; K = 9; KP = 9;
    wq = P + 896; inv = P + 6288; beta = P + 6320;
  } else if (blk < 112) {
    c = blk - 64; w = wC; g = gC; b = bC; m = mC; v = vC; K = 32; KP = 32;
    wq = P + 1184; inv = P + 6352; beta = P + 6400;
  } else if (blk < 160) {
    c = blk - 112; w = wD; g = gD; b = bD; m = mD; v = vD; K = 9; KP = 9;
    wq = P + 2720; inv = P + 6448; beta = P + 6496;
  } else {
    c = blk - 160; w = wE; g = gE; b = bE; m = mE; v = vE; K = 48; KP = 48;
    wq = P + 3152; inv = P + 6544; beta = P + 6608;
  }
  const float* wc = w + (size_t)c * K;
  float a = (t < K) ? fabsf(wc[t]) : 0.0f;
#pragma unroll
  for (int off = 32; off >= 1; off >>= 1) a = fmaxf(a, __shfl_xor(a, off));
  float s = fmaxf(a / 7.0f, 1e-8f);
  if (t < K) {
    float q = rintf(wc[t] / s);  // round half-to-even, same as jnp.round
    q = fminf(7.0f, fmaxf(-7.0f, q));
    wq[(size_t)c * KP + t] = q * s;
  } else if (t < KP) {
    wq[(size_t)c * KP + t] = 0.0f;
  }
  if (t == 0) {
    float iv = g[c] / sqrtf(v[c] + BN_EPS);
    inv[c] = iv;
    beta[c] = b[c] - m[c] * iv;
  }
}

// ---------------------------------------------------------------------------
// Stage 1: conv 3x3 s2 p0, 3->32, fp32 [8,3,512,1024] -> uint4 codes
// [8,32,255,512(pad)]. Lane = oc; weights persistent in VGPRs.
// __launch_bounds__(256, 2): empirical VGPR-cap mapping on this toolchain is
// arg4 -> 64 regs (round-5 pw spill evidence), so arg2 -> 128 regs, which
// fits the ~90 live regs this design needs (w[27]+rr[17]+acc[8]+addr).
// Round-4 default (no hint) chose 36 VGPR and rematerialized/re-loaded
// weights every s-iter (VALU ~2.2x bloat).
// ---------------------------------------------------------------------------
__global__ __launch_bounds__(256, 2) void stage1_kernel(
    const float* __restrict__ x, const float* __restrict__ P,
    const float* __restrict__ s1p, uint8_t* __restrict__ out) {
  __shared__ float tin[9 * 132];     // (ic*3+kh) x 132 cols
  __shared__ uint8_t tout[32 * 68];  // oc x 64 codes (+4 pad)
  int bid = blockIdx.x;              // n*255*8 + oy*8 + oxg
  int oxg = bid & 7;
  int t2 = bid >> 3;
  int oy = t2 % 255;
  int n = t2 / 255;
  int iy = 2 * oy;
  int ix0 = oxg * 128;
  // stage input tile: 9 rows x 33 float4
  {
    const float* xb = x + ((size_t)n * 3) * 512 * 1024;
    int idx = threadIdx.x;
#pragma unroll
    for (int rep = 0; rep < 2; rep++, idx += 256) {
      if (idx < 297) {
        int r = idx / 33, c4 = idx % 33;  // r = ic*3+kh
        int ic = r / 3, kh = r % 3;
        int col = ix0 + c4 * 4;
        float4 f = make_float4(0.f, 0.f, 0.f, 0.f);
        if (col <= 1020)
          f = *(const float4*)(xb + ((size_t)ic * 512 + iy + kh) * 1024 + col);
        *(float4*)&tin[r * 132 + c4 * 4] = f;
      }
    }
  }
  int oc = threadIdx.x & 31;
  int pg = threadIdx.x >> 5;  // 0..7 -> px = pg*8 .. pg*8+7
  float w[28];
#pragma unroll
  for (int tI = 0; tI < 7; tI++) {
    float4 f = *(const float4*)(P + oc * 28 + 4 * tI);
    w[4 * tI] = f.x; w[4 * tI + 1] = f.y;
    w[4 * tI + 2] = f.z; w[4 * tI + 3] = f.w;
  }
  float iv = P[6224 + oc], bt = P[6256 + oc];
  float s1 = *s1p;
  __syncthreads();
  float acc[8] = {0, 0, 0, 0, 0, 0, 0, 0};
#pragma unroll
  for (int s = 0; s < 9; s++) {
    float rr[17];
    const float* rp = &tin[s * 132 + pg * 16];
#pragma unroll
    for (int tI = 0; tI < 4; tI++) {
      float4 f = *(const float4*)(rp + 4 * tI);
      rr[4 * tI] = f.x; rr[4 * tI + 1] = f.y;
      rr[4 * tI + 2] = f.z; rr[4 * tI + 3] = f.w;
    }
    rr[16] = rp[16];
#pragma unroll
    for (int kw = 0; kw < 3; kw++) {
      float wv = w[s * 3 + kw];
#pragma unroll
      for (int k = 0; k < 8; k++)
        acc[k] = fmaf(rr[2 * k + kw], wv, acc[k]);
    }
  }
  uint32_t pk0 = 0, pk1 = 0;
#pragma unroll
  for (int k = 0; k < 8; k++) {
    float y = fmaf(acc[k], iv, bt);
    uint32_t q = (uint32_t)fminf(AQ_MAX, fmaxf(0.0f, rintf(y / s1)));
    if (k < 4) pk0 |= q << (8 * k); else pk1 |= q << (8 * (k - 4));
  }
  *(uint32_t*)&tout[oc * 68 + pg * 8] = pk0;
  *(uint32_t*)&tout[oc * 68 + pg * 8 + 4] = pk1;
  __syncthreads();
  size_t obase = (((size_t)n * 32) * 255 + oy) * 512 + oxg * 64;
  int c4 = (threadIdx.x & 15) * 4;
  int ocs = threadIdx.x >> 4;  // 0..15
#pragma unroll
  for (int p = 0; p < 2; p++) {
    int o = p * 16 + ocs;
    uint32_t val = *(const uint32_t*)&tout[o * 68 + c4];
    *(uint32_t*)(out + obase + (size_t)o * (255 * 512) + c4) = val;
  }
}

// ---------------------------------------------------------------------------
// Depthwise 3x3 s2 p1, codes in -> codes out. 4 output px/thread.
// ---------------------------------------------------------------------------
template <int C, int IH, int IWL, int IWP, int OH, int OW>
__global__ __launch_bounds__(256) void dw_kernel(
    const uint8_t* __restrict__ in, const float* __restrict__ wq,
    const float* __restrict__ inv, const float* __restrict__ beta,
    const float* __restrict__ sin_p, const float* __restrict__ sout_p,
    uint8_t* __restrict__ out) {
  constexpr int GX = OW / 4;
  int tid = blockIdx.x * 256 + threadIdx.x;
  int oxg = tid % GX;
  int t2 = tid / GX;
  int oy = t2 % OH;
  int t3 = t2 / OH;
  int c = __builtin_amdgcn_readfirstlane(t3 % C);
  int n = __builtin_amdgcn_readfirstlane(t3 / C);
  float s_in = *sin_p, s_out = *sout_p;
  const float* wc = wq + c * 9;  // uniform -> s_load
  float w[9];
#pragma unroll
  for (int j = 0; j < 9; j++) w[j] = wc[j];
  float iv = inv[c], bt = beta[c];
  int c0 = oxg * 8;
  const uint8_t* chan = in + ((size_t)(n * C + c)) * IH * IWP;
  float xr[3][9];
#pragma unroll
  for (int kh = 0; kh < 3; kh++) {
    int iy = 2 * oy + kh - 1;
    if (iy >= 0 && iy < IH) {
      const uint8_t* rp = chan + (size_t)iy * IWP;
      uint2 u = *(const uint2*)(rp + c0);
      xr[kh][0] = (oxg > 0) ? (float)rp[c0 - 1] : 0.0f;
#pragma unroll
      for (int j = 0; j < 4; j++) xr[kh][1 + j] = (float)((u.x >> (8 * j)) & 255u);
#pragma unroll
      for (int j = 0; j < 4; j++) xr[kh][5 + j] = (float)((u.y >> (8 * j)) & 255u);
      if (IWL < IWP && oxg == GX - 1) xr[kh][8] = 0.0f;
    } else {
#pragma unroll
      for (int j = 0; j < 9; j++) xr[kh][j] = 0.0f;
    }
  }
#pragma unroll
  for (int kh = 0; kh < 3; kh++)
#pragma unroll
    for (int j = 0; j < 9; j++) xr[kh][j] *= s_in;
  float acc[4] = {0, 0, 0, 0};
#pragma unroll
  for (int kh = 0; kh < 3; kh++)
#pragma unroll
    for (int kw = 0; kw < 3; kw++) {
      float wv = w[kh * 3 + kw];
#pragma unroll
      for (int p = 0; p < 4; p++) acc[p] = fmaf(xr[kh][2 * p + kw], wv, acc[p]);
    }
  uint32_t pack = 0;
#pragma unroll
  for (int p = 0; p < 4; p++) {
    float y = fmaf(acc[p], iv, bt);
    float q = fminf(AQ_MAX, fmaxf(0.0f, rintf(y / s_out)));
    pack |= ((uint32_t)q) << (8 * p);
  }
  *(uint32_t*)(out + ((size_t)(n * C + c) * OH + oy) * OW + c0 / 2) = pack;
}

// ---------------------------------------------------------------------------
// Pointwise 1x1, oc-chunked across blocks (chunk wave-uniform -> s_load
// weights). 2 px/thread. FINAL=true writes dequantized fp32.
// NOTE: plain __launch_bounds__(256). Round 5 showed (256,4) caps VGPR at 64
// on this toolchain -> xa/xb spill to scratch -> 282 MB WRITE, 2.4x slower.
// ---------------------------------------------------------------------------
template <int IC, int OC, int CHUNK, int HW, bool FINAL>
__global__ __launch_bounds__(256) void pw_kernel(
    const uint8_t* __restrict__ in, const float* __restrict__ Pw,
    const float* __restrict__ Pinv, const float* __restrict__ Pbeta,
    const float* __restrict__ sin_p, const float* __restrict__ sout_p,
    void* __restrict__ outv) {
  constexpr int NCH = OC / CHUNK;
  constexpr int PG = HW / 2;
  int bid = blockIdx.x;
  int chunk = bid % NCH;
  int pb = bid / NCH;
  int tpx = pb * 256 + threadIdx.x;
  int px0 = (tpx % PG) * 2;
  int n = __builtin_amdgcn_readfirstlane(tpx / PG);
  float s_in = *sin_p, s_out = *sout_p;
  const uint8_t* ib = in + (size_t)n * IC * HW + px0;
  float xa[IC], xb[IC];
#pragma unroll
  for (int ic = 0; ic < IC; ic++) {
    uint16_t u = *(const uint16_t*)(ib + (size_t)ic * HW);
    xa[ic] = (float)(u & 255u) * s_in;
    xb[ic] = (float)(u >> 8) * s_in;
  }
  int oc0 = chunk * CHUNK;
#pragma unroll 2
  for (int oc = oc0; oc < oc0 + CHUNK; oc++) {
    const float* wp = Pw + oc * IC;  // uniform -> s_load
    float w[IC];
#pragma unroll
    for (int ic = 0; ic < IC; ic++) w[ic] = wp[ic];
    float a0 = 0, a1 = 0;
#pragma unroll
    for (int ic = 0; ic < IC; ic++) {
      a0 = fmaf(xa[ic], w[ic], a0);
      a1 = fmaf(xb[ic], w[ic], a1);
    }
    float iv = Pinv[oc], bt = Pbeta[oc];
    float y0 = fmaf(a0, iv, bt), y1 = fmaf(a1, iv, bt);
    float q0 = fminf(AQ_MAX, fmaxf(0.0f, rintf(y0 / s_out)));
    float q1 = fminf(AQ_MAX, fmaxf(0.0f, rintf(y1 / s_out)));
    if (FINAL) {
      float2 o;
      o.x = q0 * s_out; o.y = q1 * s_out;
      *(float2*)((float*)outv + (size_t)(n * OC + oc) * HW + px0) = o;
    } else {
      uint16_t pk = (uint16_t)((uint32_t)q0 | ((uint32_t)q1 << 8));
      *(uint16_t*)((uint8_t*)outv + (size_t)(n * OC + oc) * HW + px0) = pk;
    }
  }
}

extern "C" void kernel_launch(void* const* d_in, const int* in_sizes, int n_in,
                              void* d_out, int out_size, void* d_ws, size_t ws_size,
                              hipStream_t stream) {
  const float* x    = (const float*)d_in[0];
  const float* w1   = (const float*)d_in[1];
  const float* g1   = (const float*)d_in[2];
  const float* b1   = (const float*)d_in[3];
  const float* m1   = (const float*)d_in[4];
  const float* v1   = (const float*)d_in[5];
  const float* s1   = (const float*)d_in[6];
  const float* wdw1 = (const float*)d_in[7];
  const float* g2   = (const float*)d_in[8];
  const float* b2   = (const float*)d_in[9];
  const float* m2   = (const float*)d_in[10];
  const float* v2   = (const float*)d_in[11];
  const float* s2   = (const float*)d_in[12];
  const float* wpw1 = (const float*)d_in[13];
  const float* g3   = (const float*)d_in[14];
  const float* b3   = (const float*)d_in[15];
  const float* m3   = (const float*)d_in[16];
  const float* v3   = (const float*)d_in[17];
  const float* s3   = (const float*)d_in[18];
  const float* wdw2 = (const float*)d_in[19];
  const float* g4   = (const float*)d_in[20];
  const float* b4   = (const float*)d_in[21];
  const float* m4   = (const float*)d_in[22];
  const float* v4   = (const float*)d_in[23];
  const float* s4   = (const float*)d_in[24];
  const float* wpw2 = (const float*)d_in[25];
  const float* g5   = (const float*)d_in[26];
  const float* b5   = (const float*)d_in[27];
  const float* m5   = (const float*)d_in[28];
  const float* v5   = (const float*)d_in[29];
  const float* s5   = (const float*)d_in[30];

  float* P = (float*)d_ws;
  float* wq2  = P + 896;
  float* wq3  = P + 1184;
  float* wq4  = P + 2720;
  float* wq5  = P + 3152;
  float* inv2 = P + 6288, *beta2 = P + 6320;
  float* inv3 = P + 6352, *beta3 = P + 6400;
  float* inv4 = P + 6448, *beta4 = P + 6496;
  float* inv5 = P + 6544, *beta5 = P + 6608;

  uint8_t* ws8 = (uint8_t*)d_ws;
  uint8_t* x1 = ws8 + 32768;            // [8,32,255,512] codes: 33,423,360 B
  uint8_t* x2 = x1 + 33423360;          // [8,32,128,256]:  8,388,608 B
  uint8_t* x3 = x2 + 8388608;           // [8,48,128,256]: 12,582,912 B
  uint8_t* x4 = ws8 + 32768;            // [8,48,64,128]: aliases x1 (dead)

  prep_all<<<224, 64, 0, stream>>>(w1, g1, b1, m1, v1,
                                   wdw1, g2, b2, m2, v2,
                                   wpw1, g3, b3, m3, v3,
                                   wdw2, g4, b4, m4, v4,
                                   wpw2, g5, b5, m5, v5, P);

  // Stage 1: blocks = 8n * 255oy * 8oxg
  stage1_kernel<<<16320, 256, 0, stream>>>(x, P, s1, x1);
  // dw1: 32ch, 255x511(512) -> 128x256
  dw_kernel<32, 255, 511, 512, 128, 256>
      <<<8192, 256, 0, stream>>>(x1, wq2, inv2, beta2, s1, s2, x2);
  // pw1: 32->48 @128x256, chunk 24 (2 chunks): 512 px-blocks * 2
  pw_kernel<32, 48, 24, 32768, false>
      <<<1024, 256, 0, stream>>>(x2, wq3, inv3, beta3, s2, s3, x3);
  // dw2: 48ch, 128x256 -> 64x128
  dw_kernel<48, 128, 256, 256, 64, 128>
      <<<3072, 256, 0, stream>>>(x3, wq4, inv4, beta4, s3, s4, x4);
  // pw2: 48->64 @64x128 -> fp32, chunk 8 (8 chunks): 128 px-blocks * 8
  pw_kernel<48, 64, 8, 8192, true>
      <<<1024, 256, 0, stream>>>(x4, wq5, inv5, beta5, s4, s5, (float*)d_out);
}

// Round 7
// 118.900 us; speedup vs baseline: 2.3850x; 1.0103x over previous
//
#include <hip/hip_runtime.h>
#include <stdint.h>

#define AQ_MAX 15.0f
#define BN_EPS 1e-5f

// ---------------------------------------------------------------------------
// Merged prep: per-output-channel int4 symmetric weight fake-quant + BN fold.
// P layout (floats): wq1[32*28]@0 wq2[288]@896 wq3[1536]@1184 wq4[432]@2720
//   wq5[3072]@3152 | inv1@6224 beta1@6256 inv2@6288 beta2@6320 inv3@6352
//   beta3@6400 inv4@6448 beta4@6496 inv5@6544 beta5@6608 (end 6672)
// ---------------------------------------------------------------------------
__global__ __launch_bounds__(64) void prep_all(
    const float* __restrict__ wA, const float* __restrict__ gA,
    const float* __restrict__ bA, const float* __restrict__ mA,
    const float* __restrict__ vA,
    const float* __restrict__ wB, const float* __restrict__ gB,
    const float* __restrict__ bB, const float* __restrict__ mB,
    const float* __restrict__ vB,
    const float* __restrict__ wC, const float* __restrict__ gC,
    const float* __restrict__ bC, const float* __restrict__ mC,
    const float* __restrict__ vC,
    const float* __restrict__ wD, const float* __restrict__ gD,
    const float* __restrict__ bD, const float* __restrict__ mD,
    const float* __restrict__ vD,
    const float* __restrict__ wE, const float* __restrict__ gE,
    const float* __restrict__ bE, const float* __restrict__ mE,
    const float* __restrict__ vE,
    float* __restrict__ P) {
  int blk = blockIdx.x, t = threadIdx.x;
  const float *w, *g, *b, *m, *v;
  float *wq, *inv, *beta;
  int K, KP, c;
  if (blk < 32) {
    c = blk; w = wA; g = gA; b = bA; m = mA; v = vA; K = 27; KP = 28;
    wq = P + 0; inv = P + 6224; beta = P + 6256;
  } else if (blk < 64) {
    c = blk - 32; w = wB; g = gB; b = bB; m = mB; v = vB; K = 9; KP = 9;
    wq = P + 896; inv = P + 6288; beta = P + 6320;
  } else if (blk < 112) {
    c = blk - 64; w = wC; g = gC; b = bC; m = mC; v = vC; K = 32; KP = 32;
    wq = P + 1184; inv = P + 6352; beta = P + 6400;
  } else if (blk < 160) {
    c = blk - 112; w = wD; g = gD; b = bD; m = mD; v = vD; K = 9; KP = 9;
    wq = P + 2720; inv = P + 6448; beta = P + 6496;
  } else {
    c = blk - 160; w = wE; g = gE; b = bE; m = mE; v = vE; K = 48; KP = 48;
    wq = P + 3152; inv = P + 6544; beta = P + 6608;
  }
  const float* wc = w + (size_t)c * K;
  float a = (t < K) ? fabsf(wc[t]) : 0.0f;
#pragma unroll
  for (int off = 32; off >= 1; off >>= 1) a = fmaxf(a, __shfl_xor(a, off));
  float s = fmaxf(a / 7.0f, 1e-8f);
  if (t < K) {
    float q = rintf(wc[t] / s);  // round half-to-even, same as jnp.round
    q = fminf(7.0f, fmaxf(-7.0f, q));
    wq[(size_t)c * KP + t] = q * s;
  } else if (t < KP) {
    wq[(size_t)c * KP + t] = 0.0f;
  }
  if (t == 0) {
    float iv = g[c] / sqrtf(v[c] + BN_EPS);
    inv[c] = iv;
    beta[c] = b[c] - m[c] * iv;
  }
}

// ---------------------------------------------------------------------------
// Stage 1 v4: conv 3x3 s2 p0, 3->32, fp32 [8,3,512,1024] -> uint4 codes
// [8,32,255,512(pad; logical 511)]. ZERO LDS: round-6 counters showed the
// LDS-staged version was LDS-pipe-bound (45 ds_read_b128/thread ~= 52us/CU).
// Here: thread = 2 output px, taps r[9][5] in VGPRs (18 VMEM loads), weights
// wave-uniform via s_load (SGPR operands, scalar pipe overlaps VALU).
// ---------------------------------------------------------------------------
__global__ __launch_bounds__(256) void stage1_kernel(
    const float* __restrict__ x, const float* __restrict__ P,
    const float* __restrict__ s1p, uint8_t* __restrict__ out) {
  int tid = blockIdx.x * 256 + threadIdx.x;  // 8*255*256 = 522,240 threads
  int gx = tid & 255;                        // 2-px group along ox
  int t2 = tid >> 8;
  int oy = t2 % 255;
  int n = t2 / 255;
  float s1 = *s1p;
  int ix0 = gx * 4, iy = 2 * oy;
  bool tailok = (ix0 + 4) < 1024;  // tap 4 only feeds the dead pad px at gx=255
  float r[9][5];
#pragma unroll
  for (int ic = 0; ic < 3; ic++)
#pragma unroll
    for (int kh = 0; kh < 3; kh++) {
      const float* bp = x + (((size_t)(n * 3 + ic)) * 512 + (iy + kh)) * 1024 + ix0;
      float4 f = *(const float4*)bp;
      int s = ic * 3 + kh;
      r[s][0] = f.x; r[s][1] = f.y; r[s][2] = f.z; r[s][3] = f.w;
      r[s][4] = tailok ? bp[4] : 0.0f;
    }
  size_t obase = (((size_t)n * 32) * 255 + oy) * 512 + gx * 2;
#pragma unroll 2
  for (int oc = 0; oc < 32; oc++) {
    const float* wp = P + oc * 28;  // wave-uniform -> s_load_dwordx4 chain
    float w[27];
#pragma unroll
    for (int j = 0; j < 27; j++) w[j] = wp[j];
    float a0 = 0.0f, a1 = 0.0f;
#pragma unroll
    for (int s = 0; s < 9; s++) {
#pragma unroll
      for (int kw = 0; kw < 3; kw++) {
        float wv = w[s * 3 + kw];
        a0 = fmaf(r[s][0 + kw], wv, a0);
        a1 = fmaf(r[s][2 + kw], wv, a1);
      }
    }
    float iv = P[6224 + oc], bt = P[6256 + oc];
    float y0 = fmaf(a0, iv, bt), y1 = fmaf(a1, iv, bt);
    uint32_t q0 = (uint32_t)fminf(AQ_MAX, fmaxf(0.0f, rintf(y0 / s1)));
    uint32_t q1 = (uint32_t)fminf(AQ_MAX, fmaxf(0.0f, rintf(y1 / s1)));
    uint16_t pk = (uint16_t)(q0 | (q1 << 8));
    *(uint16_t*)(out + obase + (size_t)oc * (255 * 512)) = pk;
  }
}

// ---------------------------------------------------------------------------
// Depthwise 3x3 s2 p1, codes in -> codes out. 4 output px/thread.
// ---------------------------------------------------------------------------
template <int C, int IH, int IWL, int IWP, int OH, int OW>
__global__ __launch_bounds__(256) void dw_kernel(
    const uint8_t* __restrict__ in, const float* __restrict__ wq,
    const float* __restrict__ inv, const float* __restrict__ beta,
    const float* __restrict__ sin_p, const float* __restrict__ sout_p,
    uint8_t* __restrict__ out) {
  constexpr int GX = OW / 4;
  int tid = blockIdx.x * 256 + threadIdx.x;
  int oxg = tid % GX;
  int t2 = tid / GX;
  int oy = t2 % OH;
  int t3 = t2 / OH;
  int c = __builtin_amdgcn_readfirstlane(t3 % C);
  int n = __builtin_amdgcn_readfirstlane(t3 / C);
  float s_in = *sin_p, s_out = *sout_p;
  const float* wc = wq + c * 9;  // uniform -> s_load
  float w[9];
#pragma unroll
  for (int j = 0; j < 9; j++) w[j] = wc[j];
  float iv = inv[c], bt = beta[c];
  int c0 = oxg * 8;
  const uint8_t* chan = in + ((size_t)(n * C + c)) * IH * IWP;
  float xr[3][9];
#pragma unroll
  for (int kh = 0; kh < 3; kh++) {
    int iy = 2 * oy + kh - 1;
    if (iy >= 0 && iy < IH) {
      const uint8_t* rp = chan + (size_t)iy * IWP;
      uint2 u = *(const uint2*)(rp + c0);
      xr[kh][0] = (oxg > 0) ? (float)rp[c0 - 1] : 0.0f;
#pragma unroll
      for (int j = 0; j < 4; j++) xr[kh][1 + j] = (float)((u.x >> (8 * j)) & 255u);
#pragma unroll
      for (int j = 0; j < 4; j++) xr[kh][5 + j] = (float)((u.y >> (8 * j)) & 255u);
      if (IWL < IWP && oxg == GX - 1) xr[kh][8] = 0.0f;
    } else {
#pragma unroll
      for (int j = 0; j < 9; j++) xr[kh][j] = 0.0f;
    }
  }
#pragma unroll
  for (int kh = 0; kh < 3; kh++)
#pragma unroll
    for (int j = 0; j < 9; j++) xr[kh][j] *= s_in;
  float acc[4] = {0, 0, 0, 0};
#pragma unroll
  for (int kh = 0; kh < 3; kh++)
#pragma unroll
    for (int kw = 0; kw < 3; kw++) {
      float wv = w[kh * 3 + kw];
#pragma unroll
      for (int p = 0; p < 4; p++) acc[p] = fmaf(xr[kh][2 * p + kw], wv, acc[p]);
    }
  uint32_t pack = 0;
#pragma unroll
  for (int p = 0; p < 4; p++) {
    float y = fmaf(acc[p], iv, bt);
    float q = fminf(AQ_MAX, fmaxf(0.0f, rintf(y / s_out)));
    pack |= ((uint32_t)q) << (8 * p);
  }
  *(uint32_t*)(out + ((size_t)(n * C + c) * OH + oy) * OW + c0 / 2) = pack;
}

// ---------------------------------------------------------------------------
// Pointwise 1x1, oc-chunked across blocks (chunk wave-uniform -> s_load
// weights). 2 px/thread. FINAL=true writes dequantized fp32.
// Plain __launch_bounds__(256): round 5 showed (256,4) caps VGPR at 64 ->
// xa/xb spill to scratch -> 282 MB WRITE, 2.4x slower.
// ---------------------------------------------------------------------------
template <int IC, int OC, int CHUNK, int HW, bool FINAL>
__global__ __launch_bounds__(256) void pw_kernel(
    const uint8_t* __restrict__ in, const float* __restrict__ Pw,
    const float* __restrict__ Pinv, const float* __restrict__ Pbeta,
    const float* __restrict__ sin_p, const float* __restrict__ sout_p,
    void* __restrict__ outv) {
  constexpr int NCH = OC / CHUNK;
  constexpr int PG = HW / 2;
  int bid = blockIdx.x;
  int chunk = bid % NCH;
  int pb = bid / NCH;
  int tpx = pb * 256 + threadIdx.x;
  int px0 = (tpx % PG) * 2;
  int n = __builtin_amdgcn_readfirstlane(tpx / PG);
  float s_in = *sin_p, s_out = *sout_p;
  const uint8_t* ib = in + (size_t)n * IC * HW + px0;
  float xa[IC], xb[IC];
#pragma unroll
  for (int ic = 0; ic < IC; ic++) {
    uint16_t u = *(const uint16_t*)(ib + (size_t)ic * HW);
    xa[ic] = (float)(u & 255u) * s_in;
    xb[ic] = (float)(u >> 8) * s_in;
  }
  int oc0 = chunk * CHUNK;
#pragma unroll 2
  for (int oc = oc0; oc < oc0 + CHUNK; oc++) {
    const float* wp = Pw + oc * IC;  // uniform -> s_load
    float w[IC];
#pragma unroll
    for (int ic = 0; ic < IC; ic++) w[ic] = wp[ic];
    float a0 = 0, a1 = 0;
#pragma unroll
    for (int ic = 0; ic < IC; ic++) {
      a0 = fmaf(xa[ic], w[ic], a0);
      a1 = fmaf(xb[ic], w[ic], a1);
    }
    float iv = Pinv[oc], bt = Pbeta[oc];
    float y0 = fmaf(a0, iv, bt), y1 = fmaf(a1, iv, bt);
    float q0 = fminf(AQ_MAX, fmaxf(0.0f, rintf(y0 / s_out)));
    float q1 = fminf(AQ_MAX, fmaxf(0.0f, rintf(y1 / s_out)));
    if (FINAL) {
      float2 o;
      o.x = q0 * s_out; o.y = q1 * s_out;
      *(float2*)((float*)outv + (size_t)(n * OC + oc) * HW + px0) = o;
    } else {
      uint16_t pk = (uint16_t)((uint32_t)q0 | ((uint32_t)q1 << 8));
      *(uint16_t*)((uint8_t*)outv + (size_t)(n * OC + oc) * HW + px0) = pk;
    }
  }
}

extern "C" void kernel_launch(void* const* d_in, const int* in_sizes, int n_in,
                              void* d_out, int out_size, void* d_ws, size_t ws_size,
                              hipStream_t stream) {
  const float* x    = (const float*)d_in[0];
  const float* w1   = (const float*)d_in[1];
  const float* g1   = (const float*)d_in[2];
  const float* b1   = (const float*)d_in[3];
  const float* m1   = (const float*)d_in[4];
  const float* v1   = (const float*)d_in[5];
  const float* s1   = (const float*)d_in[6];
  const float* wdw1 = (const float*)d_in[7];
  const float* g2   = (const float*)d_in[8];
  const float* b2   = (const float*)d_in[9];
  const float* m2   = (const float*)d_in[10];
  const float* v2   = (const float*)d_in[11];
  const float* s2   = (const float*)d_in[12];
  const float* wpw1 = (const float*)d_in[13];
  const float* g3   = (const float*)d_in[14];
  const float* b3   = (const float*)d_in[15];
  const float* m3   = (const float*)d_in[16];
  const float* v3   = (const float*)d_in[17];
  const float* s3   = (const float*)d_in[18];
  const float* wdw2 = (const float*)d_in[19];
  const float* g4   = (const float*)d_in[20];
  const float* b4   = (const float*)d_in[21];
  const float* m4   = (const float*)d_in[22];
  const float* v4   = (const float*)d_in[23];
  const float* s4   = (const float*)d_in[24];
  const float* wpw2 = (const float*)d_in[25];
  const float* g5   = (const float*)d_in[26];
  const float* b5   = (const float*)d_in[27];
  const float* m5   = (const float*)d_in[28];
  const float* v5   = (const float*)d_in[29];
  const float* s5   = (const float*)d_in[30];

  float* P = (float*)d_ws;
  float* wq2  = P + 896;
  float* wq3  = P + 1184;
  float* wq4  = P + 2720;
  float* wq5  = P + 3152;
  float* inv2 = P + 6288, *beta2 = P + 6320;
  float* inv3 = P + 6352, *beta3 = P + 6400;
  float* inv4 = P + 6448, *beta4 = P + 6496;
  float* inv5 = P + 6544, *beta5 = P + 6608;

  uint8_t* ws8 = (uint8_t*)d_ws;
  uint8_t* x1 = ws8 + 32768;            // [8,32,255,512] codes: 33,423,360 B
  uint8_t* x2 = x1 + 33423360;          // [8,32,128,256]:  8,388,608 B
  uint8_t* x3 = x2 + 8388608;           // [8,48,128,256]: 12,582,912 B
  uint8_t* x4 = ws8 + 32768;            // [8,48,64,128]: aliases x1 (dead)

  prep_all<<<224, 64, 0, stream>>>(w1, g1, b1, m1, v1,
                                   wdw1, g2, b2, m2, v2,
                                   wpw1, g3, b3, m3, v3,
                                   wdw2, g4, b4, m4, v4,
                                   wpw2, g5, b5, m5, v5, P);

  // Stage 1: 8*255*256 threads, 2 px each
  stage1_kernel<<<2040, 256, 0, stream>>>(x, P, s1, x1);
  // dw1: 32ch, 255x511(512) -> 128x256
  dw_kernel<32, 255, 511, 512, 128, 256>
      <<<8192, 256, 0, stream>>>(x1, wq2, inv2, beta2, s1, s2, x2);
  // pw1: 32->48 @128x256, chunk 24 (2 chunks): 512 px-blocks * 2
  pw_kernel<32, 48, 24, 32768, false>
      <<<1024, 256, 0, stream>>>(x2, wq3, inv3, beta3, s2, s3, x3);
  // dw2: 48ch, 128x256 -> 64x128
  dw_kernel<48, 128, 256, 256, 64, 128>
      <<<3072, 256, 0, stream>>>(x3, wq4, inv4, beta4, s3, s4, x4);
  // pw2: 48->64 @64x128 -> fp32, chunk 8 (8 chunks): 128 px-blocks * 8
  pw_kernel<48, 64, 8, 8192, true>
      <<<1024, 256, 0, stream>>>(x4, wq5, inv5, beta5, s4, s5, (float*)d_out);
}